// Round 19
// baseline (5676.167 us; speedup 1.0000x reference)
//
#include <hip/hip_runtime.h>

#define B_   64
#define C_   256
#define D_   128
#define HW_  1024
#define K_   1024
#define N_   65536
#define MARGIN_PREF 1.2e-3f

typedef __attribute__((ext_vector_type(8)))  short short8;
typedef __attribute__((ext_vector_type(4)))  float f32x4;
typedef __attribute__((ext_vector_type(16))) float f32x16;

__device__ __forceinline__ unsigned short f2bf(float f) {   // RNE f32->bf16
    unsigned u = __float_as_uint(f);
    return (unsigned short)((u + 0x7FFFu + ((u >> 16) & 1u)) >> 16);
}
__device__ __forceinline__ unsigned long long packdk(float d, int k) {  // order-preserving
    unsigned u = __float_as_uint(d);
    u = (u & 0x80000000u) ? ~u : (u | 0x80000000u);
    return ((unsigned long long)u << 10) | (unsigned)k;
}
__device__ __forceinline__ unsigned long long min64(unsigned long long a, unsigned long long b) {
    return a < b ? a : b;
}

// numpy pairwise-sum emulation, n=128 — scalar 8-accumulator tree (verified R4-R18)
template <typename F>
__device__ __forceinline__ float np_sum128(F ld) {
#pragma clang fp contract(off)
    float r0 = ld(0), r1 = ld(1), r2 = ld(2), r3 = ld(3);
    float r4 = ld(4), r5 = ld(5), r6 = ld(6), r7 = ld(7);
#pragma unroll
    for (int i = 8; i < 128; i += 8) {
        r0 = r0 + ld(i + 0); r1 = r1 + ld(i + 1);
        r2 = r2 + ld(i + 2); r3 = r3 + ld(i + 3);
        r4 = r4 + ld(i + 4); r5 = r5 + ld(i + 5);
        r6 = r6 + ld(i + 6); r7 = r7 + ld(i + 7);
    }
    return ((r0 + r1) + (r2 + r3)) + ((r4 + r5) + (r6 + r7));
}

// ---------------- K0: enorm (np bins) + embed -> bf16, PRE-SWIZZLED rows ----------------
__global__ __launch_bounds__(256) void k0_norms(const float* __restrict__ embed,
                                                float* __restrict__ enorm,
                                                unsigned short* __restrict__ ebf) {
#pragma clang fp contract(off)
    int k = blockIdx.x * 256 + threadIdx.x;
    if (k >= K_) return;
    const float* e = embed + (size_t)k * D_;
    enorm[k] = np_sum128([&](int i) { float v = e[i]; return v * v; });
    const int sw = (k & 7) << 4;
    char* rowp = (char*)ebf + ((size_t)k << 8);
#pragma unroll
    for (int j = 0; j < 16; ++j) {            // 16B chunks, swizzle preserves chunks
        short8 v;
#pragma unroll
        for (int q = 0; q < 8; ++q) v[q] = (short)f2bf(e[j * 8 + q]);
        *(short8*)(rowp + ((j * 16) ^ sw)) = v;
    }
}

// ---------------- K1: einsum-f32 emulation (sequential c, mul+add, no FMA) + bf16 copy ----------------
__global__ __launch_bounds__(256) void k1_proj(const float* __restrict__ z,
                                               const float* __restrict__ w,
                                               const float* __restrict__ bias,
                                               float* __restrict__ zp,
                                               unsigned short* __restrict__ zbf) {
#pragma clang fp contract(off)
    __shared__ float zs[64][64];
    __shared__ float wsh[64][128];
    const int b   = blockIdx.x >> 4;
    const int hw0 = (blockIdx.x & 15) << 6;
    const int t   = threadIdx.x;
    const int hwg = (t & 7) * 8;
    const int dg  = (t >> 3) * 4;

    float acc[8][4];
#pragma unroll
    for (int i = 0; i < 8; ++i)
#pragma unroll
        for (int j = 0; j < 4; ++j) acc[i][j] = 0.f;

    for (int ct = 0; ct < C_; ct += 64) {
        __syncthreads();
#pragma unroll
        for (int i = 0; i < 16; ++i) {
            int idx = i * 256 + t;
            int cc = idx >> 6, hwl = idx & 63;
            zs[cc][hwl] = z[(((size_t)b * C_ + ct + cc) << 10) + hw0 + hwl];
        }
#pragma unroll
        for (int i = 0; i < 32; ++i) {
            int idx = i * 256 + t;
            int cc = idx >> 7, d = idx & 127;
            wsh[cc][d] = w[(size_t)d * C_ + ct + cc];
        }
        __syncthreads();
#pragma unroll 2
        for (int cc = 0; cc < 64; ++cc) {
            float4 za = *(const float4*)&zs[cc][hwg];
            float4 zb = *(const float4*)&zs[cc][hwg + 4];
            float4 wv = *(const float4*)&wsh[cc][dg];
            float zv[8]  = {za.x, za.y, za.z, za.w, zb.x, zb.y, zb.z, zb.w};
            float wva[4] = {wv.x, wv.y, wv.z, wv.w};
#pragma unroll
            for (int i = 0; i < 8; ++i)
#pragma unroll
                for (int j = 0; j < 4; ++j) {
                    float p = zv[i] * wva[j];
                    acc[i][j] = acc[i][j] + p;
                }
        }
    }
#pragma unroll
    for (int i = 0; i < 8; ++i)
#pragma unroll
        for (int j = 0; j < 4; ++j) {
            float v = acc[i][j] + bias[dg + j];
            size_t off = (((size_t)b * HW_ + hw0 + hwg + i) << 7) + dg + j;
            zp[off]  = v;
            zbf[off] = f2bf(v);
        }
}

// ---------------- K0z: znorm[n] = np.sum(zf*zf) per row (np bins) ----------------
__global__ __launch_bounds__(256) void k0z_znorm(const float* __restrict__ zp,
                                                 float* __restrict__ znorm) {
#pragma clang fp contract(off)
    __shared__ float zl[64][129];          // +1 pad: conflict-free column reads
    const int t = threadIdx.x, n0 = blockIdx.x * 64;
#pragma unroll
    for (int i = 0; i < 32; ++i) {
        int idx = i * 256 + t;
        zl[idx >> 7][idx & 127] = zp[(size_t)n0 * 128 + idx];
    }
    __syncthreads();
    if (t < 64)
        znorm[n0 + t] = np_sum128([&](int i) { float v = zl[t][i]; return v * v; });
}

// ---------------- K2: two-pass 32x32-MFMA prefilter + exact np-bin rescue ----------------
// R17 structure (two passes, dbuf global_load_lds staging, LDS enorm) with
// mfma_f32_32x32x16_bf16: one wave covers 32 rows x 32 k per tile -> half the
// waves (128-thr blocks), 8 blocks/CU (2x barrier groups), half issue per k-elem.
// C/D: col=lane&31 (z-row), row=(reg&3)+8*(reg>>2)+4*(lane>>5) (k-local) [m74/m101].
// A and B loaded with the SAME (l>>5)*8-blocked k convention -> slot permutation cancels.
__global__ __launch_bounds__(128) void k2_argmin(const unsigned short* __restrict__ zbf,
                                                 const unsigned short* __restrict__ ebf,
                                                 const float* __restrict__ zp,
                                                 const float* __restrict__ embed,
                                                 const float* __restrict__ enorm,
                                                 const float* __restrict__ znorm,
                                                 int* __restrict__ bestk_ws,
                                                 float* __restrict__ out_idx) {
    __shared__ unsigned char etile[2][32 * 256];   // 2 x (32 k-rows x 256B, pre-swizzled)
    __shared__ float els[1024];                    // enorm, block-resident
    const int t   = threadIdx.x;
    const int l   = t & 63;
    const int wid = t >> 6;                        // 0..1
    const int r0  = blockIdx.x * 64 + wid * 32;    // wave's 32 rows
    const int col = l & 31;                        // z-row within wave tile
    const int hi  = l >> 5;                        // k-slice half

    // z fragments (B operand): 8 K=16 slices; lane = z-row col, d = ks*16 + hi*8
    short8 zfrag[8];
#pragma unroll
    for (int ks = 0; ks < 8; ++ks)
        zfrag[ks] = *(const short8*)(zbf + (((size_t)(r0 + col)) << 7) + ks * 16 + hi * 8);

    // A-operand swizzled LDS offsets: e-row = col, byte col = (ks*32 + hi*16) ^ ((col&7)<<4)
    const int swz = (col & 7) << 4;
    int roff[8];
#pragma unroll
    for (int ks = 0; ks < 8; ++ks)
        roff[ks] = col * 256 + ((ks * 32 + hi * 16) ^ swz);

    const char* ebf_b = (const char*)ebf;

    auto STAGE = [&](int st, int b) {              // async 8KB k-tile -> LDS (linear dest)
#pragma unroll
        for (int i = 0; i < 4; ++i) {
            int off = i * 2048 + (t << 4);
            __builtin_amdgcn_global_load_lds(
                (const __attribute__((address_space(1))) void*)(ebf_b + ((size_t)st << 13) + off),
                (__attribute__((address_space(3))) void*)(&etile[b][off]),
                16, 0, 0);
        }
    };

    // stage enorm to LDS (coalesced, once)
#pragma unroll
    for (int i = 0; i < 8; ++i) els[i * 128 + t] = enorm[i * 128 + t];

    // ---- Pass A: f32 running MIN of dist only (branch-free, no k-tracking) ----
    float bmin0 = 1e30f, bmin1 = 1e30f;
    STAGE(0, 0);
#pragma unroll 1
    for (int st = 0; st < 32; ++st) {
        __syncthreads();                           // drains stage(st) + els writes
        if (st < 31) STAGE(st + 1, (st + 1) & 1);
        const unsigned char* buf = etile[st & 1];
        f32x16 acc = {};
#pragma unroll
        for (int ks = 0; ks < 8; ++ks) {
            short8 af = *(const short8*)(buf + roff[ks]);
            acc = __builtin_amdgcn_mfma_f32_32x32x16_bf16(af, zfrag[ks], acc, 0, 0, 0);
        }
#pragma unroll
        for (int q = 0; q < 4; ++q) {
            f32x4 en4 = *(const f32x4*)(els + st * 32 + q * 8 + hi * 4);
#pragma unroll
            for (int r = 0; r < 4; ++r) {
                float dist = fmaf(-2.f, acc[q * 4 + r], en4[r]);
                if (q & 1) bmin1 = fminf(bmin1, dist); else bmin0 = fminf(bmin0, dist);
            }
        }
    }
    float bmin = fminf(bmin0, bmin1);
    bmin = fminf(bmin, __shfl_xor(bmin, 32, 64));  // combine the row's two lanes
    const float thr = bmin + MARGIN_PREF;          // window vs TRUE row min

    // ---- Pass B: bitwise-identical recompute, collect candidates ----
    unsigned long long ca = 0, cb = 0;             // 12 x 10-bit candidate slots
    int cnt = 0;
    __syncthreads();
    STAGE(0, 0);
#pragma unroll 1
    for (int st = 0; st < 32; ++st) {
        __syncthreads();
        if (st < 31) STAGE(st + 1, (st + 1) & 1);
        const unsigned char* buf = etile[st & 1];
        f32x16 acc = {};
#pragma unroll
        for (int ks = 0; ks < 8; ++ks) {
            short8 af = *(const short8*)(buf + roff[ks]);
            acc = __builtin_amdgcn_mfma_f32_32x32x16_bf16(af, zfrag[ks], acc, 0, 0, 0);
        }
#pragma unroll
        for (int q = 0; q < 4; ++q) {
            f32x4 en4 = *(const f32x4*)(els + st * 32 + q * 8 + hi * 4);
#pragma unroll
            for (int r = 0; r < 4; ++r) {
                float dist = fmaf(-2.f, acc[q * 4 + r], en4[r]);
                if (dist < thr) {
                    int kk = st * 32 + q * 8 + hi * 4 + r;
                    if (cnt < 6)       ca |= (unsigned long long)kk << (10 * cnt);
                    else if (cnt < 12) cb |= (unsigned long long)kk << (10 * (cnt - 6));
                    ++cnt;
                }
            }
        }
    }

    // ---- Phase C: exact np-bin refine of candidates (R4-verified chain) ----
    const int myrow = r0 + col;
    const float* zrow = zp + ((size_t)myrow << 7);
    const float  zn   = znorm[myrow];
    unsigned long long best = ~0ull;

    auto refine = [&](int kk) {
#pragma clang fp contract(off)
        const float* e = embed + ((size_t)kk << 7);
        float s = 0.f;
#pragma unroll 1
        for (int d = 0; d < 128; ++d) s = fmaf(zrow[d], e[d], s);
        float T  = 2.0f * s;
        float A  = zn - T;                  // bin-maker 1 (mag ~13)
        float Bv = A + enorm[kk];           // bin-maker 2
        best = min64(best, packdk(Bv, kk)); // lex (bin, k) = np first-occurrence
    };

    if (cnt <= 12) {
#pragma unroll
        for (int i = 0; i < 6; ++i)
            if (i < cnt) refine((int)((ca >> (10 * i)) & 1023ull));
#pragma unroll
        for (int i = 6; i < 12; ++i)
            if (i < cnt) refine((int)((cb >> (10 * (i - 6))) & 1023ull));
    } else {                                // overflow fallback: lane's k-subset
#pragma unroll 1
        for (int st = 0; st < 32; ++st)
#pragma unroll
            for (int q = 0; q < 4; ++q)
#pragma unroll
                for (int r = 0; r < 4; ++r)
                    refine(st * 32 + q * 8 + hi * 4 + r);
    }
    {   // combine the row's two lanes (l, l^32)
        unsigned long long o = __shfl_xor(best, 32, 64);
        best = min64(best, o);
    }
    if (l < 32) {
        int kk = (int)(best & 1023ull);
        bestk_ws[r0 + l] = kk;
        out_idx[r0 + l]  = (float)kk;
    }
}

// ---------------- K3: gather + NCHW transpose ----------------
__global__ __launch_bounds__(256) void k3_gather(const float* __restrict__ embed,
                                                 const int* __restrict__ bestk,
                                                 float* __restrict__ out0) {
    __shared__ float tile[64][129];
    const int b   = blockIdx.x >> 4;
    const int hw0 = (blockIdx.x & 15) << 6;
    const int t   = threadIdx.x;
    const int n0  = b * HW_ + hw0;
#pragma unroll
    for (int i = 0; i < 32; ++i) {
        int idx = i * 256 + t;
        int hwl = idx >> 7, d = idx & 127;
        int k = bestk[n0 + hwl];
        tile[hwl][d] = embed[(size_t)k * 128 + d];
    }
    __syncthreads();
#pragma unroll
    for (int i = 0; i < 32; ++i) {
        int idx = i * 256 + t;
        int d = idx >> 6, hwl = idx & 63;
        out0[(((size_t)b * D_ + d) << 10) + hw0 + hwl] = tile[hwl][d];
    }
}

extern "C" void kernel_launch(void* const* d_in, const int* in_sizes, int n_in,
                              void* d_out, int out_size, void* d_ws, size_t ws_size,
                              hipStream_t stream) {
    const float* z     = (const float*)d_in[0];
    const float* pw    = (const float*)d_in[1];
    const float* pb    = (const float*)d_in[2];
    const float* embed = (const float*)d_in[3];

    float* out0 = (float*)d_out;
    float* out1 = (float*)d_out + (size_t)B_ * D_ * HW_;

    char* ws = (char*)d_ws;
    float*          zp    = (float*)ws;                                   // 32 MB
    unsigned short* zbf   = (unsigned short*)(ws + (32u << 20));          // 16 MB
    unsigned short* ebf   = (unsigned short*)(ws + (48u << 20));          // 256 KB
    float*          enorm = (float*)(ws + (48u << 20) + (256u << 10));    // 4 KB
    float*          znorm = (float*)(ws + (49u << 20));                   // 256 KB
    int*            bestk = (int*)  (ws + (50u << 20));                   // 256 KB

    hipLaunchKernelGGL(k0_norms,  dim3(4),    dim3(256), 0, stream, embed, enorm, ebf);
    hipLaunchKernelGGL(k1_proj,   dim3(1024), dim3(256), 0, stream, z, pw, pb, zp, zbf);
    hipLaunchKernelGGL(k0z_znorm, dim3(1024), dim3(256), 0, stream, zp, znorm);
    hipLaunchKernelGGL(k2_argmin, dim3(1024), dim3(128), 0, stream,
                       zbf, ebf, zp, embed, enorm, znorm, bestk, out1);
    hipLaunchKernelGGL(k3_gather, dim3(1024), dim3(256), 0, stream, embed, bestk, out0);
}

// Round 20
// 372.677 us; speedup vs baseline: 15.2308x; 15.2308x over previous
//
#include <hip/hip_runtime.h>

#define B_   64
#define C_   256
#define D_   128
#define HW_  1024
#define K_   1024
#define N_   65536
#define MARGIN_PREF 1.2e-3f

typedef __attribute__((ext_vector_type(8))) short short8;
typedef __attribute__((ext_vector_type(4))) float f32x4;

__device__ __forceinline__ unsigned short f2bf(float f) {   // RNE f32->bf16
    unsigned u = __float_as_uint(f);
    return (unsigned short)((u + 0x7FFFu + ((u >> 16) & 1u)) >> 16);
}
__device__ __forceinline__ unsigned long long packdk(float d, int k) {  // order-preserving
    unsigned u = __float_as_uint(d);
    u = (u & 0x80000000u) ? ~u : (u | 0x80000000u);
    return ((unsigned long long)u << 10) | (unsigned)k;
}
__device__ __forceinline__ unsigned long long min64(unsigned long long a, unsigned long long b) {
    return a < b ? a : b;
}

// numpy pairwise-sum emulation, n=128 — scalar 8-accumulator tree (verified R4-R19)
template <typename F>
__device__ __forceinline__ float np_sum128(F ld) {
#pragma clang fp contract(off)
    float r0 = ld(0), r1 = ld(1), r2 = ld(2), r3 = ld(3);
    float r4 = ld(4), r5 = ld(5), r6 = ld(6), r7 = ld(7);
#pragma unroll
    for (int i = 8; i < 128; i += 8) {
        r0 = r0 + ld(i + 0); r1 = r1 + ld(i + 1);
        r2 = r2 + ld(i + 2); r3 = r3 + ld(i + 3);
        r4 = r4 + ld(i + 4); r5 = r5 + ld(i + 5);
        r6 = r6 + ld(i + 6); r7 = r7 + ld(i + 7);
    }
    return ((r0 + r1) + (r2 + r3)) + ((r4 + r5) + (r6 + r7));
}

// ---------------- K0: enorm (np bins) + embed -> bf16, PRE-SWIZZLED rows ----------------
__global__ __launch_bounds__(256) void k0_norms(const float* __restrict__ embed,
                                                float* __restrict__ enorm,
                                                unsigned short* __restrict__ ebf) {
#pragma clang fp contract(off)
    int k = blockIdx.x * 256 + threadIdx.x;
    if (k >= K_) return;
    const float* e = embed + (size_t)k * D_;
    enorm[k] = np_sum128([&](int i) { float v = e[i]; return v * v; });
    const int sw = (k & 7) << 4;
    char* rowp = (char*)ebf + ((size_t)k << 8);
#pragma unroll
    for (int j = 0; j < 16; ++j) {            // 16B chunks, swizzle preserves chunks
        short8 v;
#pragma unroll
        for (int q = 0; q < 8; ++q) v[q] = (short)f2bf(e[j * 8 + q]);
        *(short8*)(rowp + ((j * 16) ^ sw)) = v;
    }
}

// ---------------- K1: einsum-f32 emulation (sequential c, mul+add, no FMA) + bf16 copy ----------------
__global__ __launch_bounds__(256) void k1_proj(const float* __restrict__ z,
                                               const float* __restrict__ w,
                                               const float* __restrict__ bias,
                                               float* __restrict__ zp,
                                               unsigned short* __restrict__ zbf) {
#pragma clang fp contract(off)
    __shared__ float zs[64][64];
    __shared__ float wsh[64][128];
    const int b   = blockIdx.x >> 4;
    const int hw0 = (blockIdx.x & 15) << 6;
    const int t   = threadIdx.x;
    const int hwg = (t & 7) * 8;
    const int dg  = (t >> 3) * 4;

    float acc[8][4];
#pragma unroll
    for (int i = 0; i < 8; ++i)
#pragma unroll
        for (int j = 0; j < 4; ++j) acc[i][j] = 0.f;

    for (int ct = 0; ct < C_; ct += 64) {
        __syncthreads();
#pragma unroll
        for (int i = 0; i < 16; ++i) {
            int idx = i * 256 + t;
            int cc = idx >> 6, hwl = idx & 63;
            zs[cc][hwl] = z[(((size_t)b * C_ + ct + cc) << 10) + hw0 + hwl];
        }
#pragma unroll
        for (int i = 0; i < 32; ++i) {
            int idx = i * 256 + t;
            int cc = idx >> 7, d = idx & 127;
            wsh[cc][d] = w[(size_t)d * C_ + ct + cc];
        }
        __syncthreads();
#pragma unroll 2
        for (int cc = 0; cc < 64; ++cc) {
            float4 za = *(const float4*)&zs[cc][hwg];
            float4 zb = *(const float4*)&zs[cc][hwg + 4];
            float4 wv = *(const float4*)&wsh[cc][dg];
            float zv[8]  = {za.x, za.y, za.z, za.w, zb.x, zb.y, zb.z, zb.w};
            float wva[4] = {wv.x, wv.y, wv.z, wv.w};
#pragma unroll
            for (int i = 0; i < 8; ++i)
#pragma unroll
                for (int j = 0; j < 4; ++j) {
                    float p = zv[i] * wva[j];
                    acc[i][j] = acc[i][j] + p;
                }
        }
    }
#pragma unroll
    for (int i = 0; i < 8; ++i)
#pragma unroll
        for (int j = 0; j < 4; ++j) {
            float v = acc[i][j] + bias[dg + j];
            size_t off = (((size_t)b * HW_ + hw0 + hwg + i) << 7) + dg + j;
            zp[off]  = v;
            zbf[off] = f2bf(v);
        }
}

// ---------------- K0z: znorm[n] = np.sum(zf*zf) per row (np bins) ----------------
__global__ __launch_bounds__(256) void k0z_znorm(const float* __restrict__ zp,
                                                 float* __restrict__ znorm) {
#pragma clang fp contract(off)
    __shared__ float zl[64][129];          // +1 pad: conflict-free column reads
    const int t = threadIdx.x, n0 = blockIdx.x * 64;
#pragma unroll
    for (int i = 0; i < 32; ++i) {
        int idx = i * 256 + t;
        zl[idx >> 7][idx & 127] = zp[(size_t)n0 * 128 + idx];
    }
    __syncthreads();
    if (t < 64)
        znorm[n0 + t] = np_sum128([&](int i) { float v = zl[t][i]; return v * v; });
}

// ---------------- K2: two-pass MFMA prefilter + exact np-bin rescue ----------------
// R17 structure EXACTLY, plus opaque-asm PIN of the loop-invariant z-fragments:
// R17's VGPR_Count=32 proved the compiler demoted zfrag and re-loaded it from
// global inside every iteration (4 serialized L2 RTTs/iter = the ~3.5us/iter
// floor). The asm identity makes zfrag non-rematerializable -> stays in VGPRs.
__global__ __launch_bounds__(256) void k2_argmin(const unsigned short* __restrict__ zbf,
                                                 const unsigned short* __restrict__ ebf,
                                                 const float* __restrict__ zp,
                                                 const float* __restrict__ embed,
                                                 const float* __restrict__ enorm,
                                                 const float* __restrict__ znorm,
                                                 int* __restrict__ bestk_ws,
                                                 float* __restrict__ out_idx) {
    __shared__ unsigned char etile[2][32 * 256];   // 2 x (32 k-rows x 256B), linear
    __shared__ float els[1024];                    // enorm, block-resident
    const int t   = threadIdx.x;
    const int l   = t & 63;
    const int wid = t >> 6;                        // 0..3
    const int r0  = (blockIdx.x * 4 + wid) * 16;   // wave's 16 rows
    const int lr  = l & 15;
    const int lh  = l >> 4;

    // z fragments (B operand): 4 d-tiles (mapping verified R9-R19), PINNED in VGPRs
    short8 zfrag[4];
#pragma unroll
    for (int dt = 0; dt < 4; ++dt) {
        zfrag[dt] = *(const short8*)(zbf + (((size_t)(r0 + lr)) << 7) + dt * 32 + lh * 8);
        asm volatile("" : "+v"(zfrag[dt]));        // opaque: cannot be remat'd from memory
    }

    // per-lane swizzled ds_read offsets (row lr, logical col dt*64+lh*16)
    const int swz = (lr & 7) << 4;
    int roff[4];
#pragma unroll
    for (int dt = 0; dt < 4; ++dt)
        roff[dt] = lr * 256 + ((dt * 64 + lh * 16) ^ swz);

    const char* ebf_b   = (const char*)ebf;
    const int   stg_off = wid * 1024;              // wave's 1KB slice per 4KB chunk

    auto STAGE = [&](int st, int b) {              // async 8KB supertile -> LDS
#pragma unroll
        for (int j = 0; j < 2; ++j) {
            int off = j * 4096 + stg_off;
            __builtin_amdgcn_global_load_lds(
                (const __attribute__((address_space(1))) void*)(ebf_b + ((size_t)st << 13) + off + (l << 4)),
                (__attribute__((address_space(3))) void*)(&etile[b][off]),
                16, 0, 0);
        }
    };

    // stage enorm to LDS (coalesced, once)
#pragma unroll
    for (int i = 0; i < 4; ++i) els[i * 256 + t] = enorm[i * 256 + t];

    // ---- Pass A: f32 running MIN of dist only (branch-free, no k-tracking) ----
    float bmin = 1e30f;
    STAGE(0, 0);
#pragma unroll 1
    for (int st = 0; st < 32; ++st) {
        __syncthreads();                           // drains stage(st) + els writes
        if (st < 31) STAGE(st + 1, (st + 1) & 1);
        const unsigned char* buf = etile[st & 1];
#pragma unroll
        for (int ks = 0; ks < 2; ++ks) {
            short8 af[4];
#pragma unroll
            for (int dt = 0; dt < 4; ++dt)
                af[dt] = *(const short8*)(buf + ks * 4096 + roff[dt]);
            f32x4 en4 = *(const f32x4*)(els + st * 32 + ks * 16 + lh * 4);  // LDS broadcast
            f32x4 acc = {0.f, 0.f, 0.f, 0.f};
#pragma unroll
            for (int dt = 0; dt < 4; ++dt)
                acc = __builtin_amdgcn_mfma_f32_16x16x32_bf16(af[dt], zfrag[dt], acc, 0, 0, 0);
#pragma unroll
            for (int reg = 0; reg < 4; ++reg)
                bmin = fminf(bmin, fmaf(-2.f, acc[reg], en4[reg]));
        }
    }
    {   // row-min across lanes {lr, lr+16, lr+32, lr+48}
        bmin = fminf(bmin, __shfl_xor(bmin, 16, 64));
        bmin = fminf(bmin, __shfl_xor(bmin, 32, 64));
    }
    const float thr = bmin + MARGIN_PREF;

    // ---- Pass B: bitwise-identical recompute, collect candidates ----
    unsigned long long ca = 0, cb = 0;             // 12 x 10-bit candidate slots
    int cnt = 0;
    __syncthreads();
    STAGE(0, 0);
#pragma unroll 1
    for (int st = 0; st < 32; ++st) {
        __syncthreads();
        if (st < 31) STAGE(st + 1, (st + 1) & 1);
        const unsigned char* buf = etile[st & 1];
#pragma unroll
        for (int ks = 0; ks < 2; ++ks) {
            short8 af[4];
#pragma unroll
            for (int dt = 0; dt < 4; ++dt)
                af[dt] = *(const short8*)(buf + ks * 4096 + roff[dt]);
            f32x4 en4 = *(const f32x4*)(els + st * 32 + ks * 16 + lh * 4);
            f32x4 acc = {0.f, 0.f, 0.f, 0.f};
#pragma unroll
            for (int dt = 0; dt < 4; ++dt)
                acc = __builtin_amdgcn_mfma_f32_16x16x32_bf16(af[dt], zfrag[dt], acc, 0, 0, 0);
#pragma unroll
            for (int reg = 0; reg < 4; ++reg) {
                float dist = fmaf(-2.f, acc[reg], en4[reg]);
                if (dist < thr) {                  // window vs TRUE row min -> np winner in set
                    int kk = st * 32 + ks * 16 + lh * 4 + reg;
                    if (cnt < 6)       ca |= (unsigned long long)kk << (10 * cnt);
                    else if (cnt < 12) cb |= (unsigned long long)kk << (10 * (cnt - 6));
                    ++cnt;
                }
            }
        }
    }

    // ---- Phase C: exact np-bin refine of candidates (R4-verified chain) ----
    const int myrow = r0 + lr;
    const float* zrow = zp + ((size_t)myrow << 7);
    const float  zn   = znorm[myrow];
    unsigned long long best = ~0ull;

    auto refine = [&](int kk) {
#pragma clang fp contract(off)
        const float* e = embed + ((size_t)kk << 7);
        float s = 0.f;
#pragma unroll 1
        for (int d = 0; d < 128; ++d) s = fmaf(zrow[d], e[d], s);
        float T  = 2.0f * s;
        float A  = zn - T;                  // bin-maker 1 (mag ~13)
        float Bv = A + enorm[kk];           // bin-maker 2
        best = min64(best, packdk(Bv, kk)); // lex (bin, k) = np first-occurrence
    };

    if (cnt <= 12) {
#pragma unroll
        for (int i = 0; i < 6; ++i)
            if (i < cnt) refine((int)((ca >> (10 * i)) & 1023ull));
#pragma unroll
        for (int i = 6; i < 12; ++i)
            if (i < cnt) refine((int)((cb >> (10 * (i - 6))) & 1023ull));
    } else {                                // overflow fallback: lane's whole 256-k subset
#pragma unroll 1
        for (int kt = 0; kt < 64; ++kt)
#pragma unroll
            for (int reg = 0; reg < 4; ++reg) refine(kt * 16 + lh * 4 + reg);
    }
    {   // row-min across lanes {lr, lr+16, lr+32, lr+48}
        unsigned long long o;
        o = __shfl_xor(best, 16, 64); best = min64(best, o);
        o = __shfl_xor(best, 32, 64); best = min64(best, o);
    }
    if (l < 16) {
        int kk = (int)(best & 1023ull);
        bestk_ws[r0 + l] = kk;
        out_idx[r0 + l]  = (float)kk;
    }
}

// ---------------- K3: gather + NCHW transpose ----------------
__global__ __launch_bounds__(256) void k3_gather(const float* __restrict__ embed,
                                                 const int* __restrict__ bestk,
                                                 float* __restrict__ out0) {
    __shared__ float tile[64][129];
    const int b   = blockIdx.x >> 4;
    const int hw0 = (blockIdx.x & 15) << 6;
    const int t   = threadIdx.x;
    const int n0  = b * HW_ + hw0;
#pragma unroll
    for (int i = 0; i < 32; ++i) {
        int idx = i * 256 + t;
        int hwl = idx >> 7, d = idx & 127;
        int k = bestk[n0 + hwl];
        tile[hwl][d] = embed[(size_t)k * 128 + d];
    }
    __syncthreads();
#pragma unroll
    for (int i = 0; i < 32; ++i) {
        int idx = i * 256 + t;
        int d = idx >> 6, hwl = idx & 63;
        out0[(((size_t)b * D_ + d) << 10) + hw0 + hwl] = tile[hwl][d];
    }
}

extern "C" void kernel_launch(void* const* d_in, const int* in_sizes, int n_in,
                              void* d_out, int out_size, void* d_ws, size_t ws_size,
                              hipStream_t stream) {
    const float* z     = (const float*)d_in[0];
    const float* pw    = (const float*)d_in[1];
    const float* pb    = (const float*)d_in[2];
    const float* embed = (const float*)d_in[3];

    float* out0 = (float*)d_out;
    float* out1 = (float*)d_out + (size_t)B_ * D_ * HW_;

    char* ws = (char*)d_ws;
    float*          zp    = (float*)ws;                                   // 32 MB
    unsigned short* zbf   = (unsigned short*)(ws + (32u << 20));          // 16 MB
    unsigned short* ebf   = (unsigned short*)(ws + (48u << 20));          // 256 KB
    float*          enorm = (float*)(ws + (48u << 20) + (256u << 10));    // 4 KB
    float*          znorm = (float*)(ws + (49u << 20));                   // 256 KB
    int*            bestk = (int*)  (ws + (50u << 20));                   // 256 KB

    hipLaunchKernelGGL(k0_norms,  dim3(4),    dim3(256), 0, stream, embed, enorm, ebf);
    hipLaunchKernelGGL(k1_proj,   dim3(1024), dim3(256), 0, stream, z, pw, pb, zp, zbf);
    hipLaunchKernelGGL(k0z_znorm, dim3(1024), dim3(256), 0, stream, zp, znorm);
    hipLaunchKernelGGL(k2_argmin, dim3(1024), dim3(256), 0, stream,
                       zbf, ebf, zp, embed, enorm, znorm, bestk, out1);
    hipLaunchKernelGGL(k3_gather, dim3(1024), dim3(256), 0, stream, embed, bestk, out0);
}